// Round 1
// baseline (968.258 us; speedup 1.0000x reference)
//
#include <hip/hip_runtime.h>
#include <math.h>

#define BB 32
#define NN 16384
#define GG 128
#define KK 64
#define HH 128
#define DD 384
#define LN_EPS 1e-5f
#define CHUNK 8192

// round-to-nearest sum of 3 squares, matching jnp.sum(x**2, -1) order, no FMA contraction
__device__ __forceinline__ float sq3(float x, float y, float z) {
    return __fadd_rn(__fadd_rn(__fmul_rn(x, x), __fmul_rn(y, y)), __fmul_rn(z, z));
}

// ---------------- prep: transpose w2 [128,384] -> w2t [384,128] ----------------
__global__ void prep_kernel(const float* __restrict__ w2, float* __restrict__ w2t) {
    int i = blockIdx.x * 256 + threadIdx.x;  // over DD*HH = 49152
    if (i < HH * DD) {
        int f = i >> 7;    // 0..383
        int k = i & 127;   // 0..127
        w2t[i] = w2[k * DD + f];
    }
}

// ---------------- FPS: one block per batch, 1024 threads, 16 pts/thread ----------------
__global__ __launch_bounds__(1024) void fps_kernel(const float* __restrict__ pts,
                                                   float* __restrict__ cent_out,
                                                   float4* __restrict__ cent_pad) {
    const int b = blockIdx.x;
    const int tid = threadIdx.x;
    const float* p = pts + (size_t)b * NN * 3;

    float x[16], y[16], z[16], dist[16];
#pragma unroll
    for (int j = 0; j < 16; j++) {
        int n = j * 1024 + tid;
        x[j] = p[n * 3 + 0];
        y[j] = p[n * 3 + 1];
        z[j] = p[n * 3 + 2];
        dist[j] = INFINITY;
    }

    __shared__ float cenx, ceny, cenz;
    __shared__ int curS;
    __shared__ float wv[16];
    __shared__ int wi[16];

    if (tid == 0) { cenx = x[0]; ceny = y[0]; cenz = z[0]; }
    __syncthreads();

    for (int it = 0; it < GG; it++) {
        float cx = cenx, cy = ceny, cz = cenz;
        if (tid == 0) {
            float* co = cent_out + ((size_t)b * GG + it) * 3;
            co[0] = cx; co[1] = cy; co[2] = cz;
            cent_pad[b * GG + it] = make_float4(cx, cy, cz, sq3(cx, cy, cz));
        }
        // distance update + local argmax (first-index tie-break: strict >)
        float bv = -INFINITY;
        int bi = 0;
#pragma unroll
        for (int j = 0; j < 16; j++) {
            float dx = __fsub_rn(x[j], cx);
            float dy = __fsub_rn(y[j], cy);
            float dz = __fsub_rn(z[j], cz);
            float d = sq3(dx, dy, dz);
            float dj = fminf(dist[j], d);
            dist[j] = dj;
            if (dj > bv) { bv = dj; bi = j * 1024 + tid; }
        }
        // wave (64-lane) argmax reduce, lower index wins ties
#pragma unroll
        for (int off = 32; off >= 1; off >>= 1) {
            float ov = __shfl_down(bv, off);
            int oi = __shfl_down(bi, off);
            if (ov > bv || (ov == bv && oi < bi)) { bv = ov; bi = oi; }
        }
        int lane = tid & 63, wid = tid >> 6;
        if (lane == 0) { wv[wid] = bv; wi[wid] = bi; }
        __syncthreads();
        if (tid == 0) {
            float fv = wv[0]; int fi = wi[0];
            for (int w = 1; w < 16; w++) {
                if (wv[w] > fv || (wv[w] == fv && wi[w] < fi)) { fv = wv[w]; fi = wi[w]; }
            }
            curS = fi;
        }
        __syncthreads();
        int cur = curS;
        // owning thread publishes the next centroid from its registers
#pragma unroll
        for (int j = 0; j < 16; j++) {
            if (cur == j * 1024 + tid) { cenx = x[j]; ceny = y[j]; cenz = z[j]; }
        }
        __syncthreads();
    }
}

// ---------------- group kernel: dist2 + exact top-64 + MLP + mean + LN ----------------
__global__ __launch_bounds__(256) void group_kernel(
    const float* __restrict__ pts, const float4* __restrict__ cent_pad,
    const float* __restrict__ w1, const float* __restrict__ b1,
    const float* __restrict__ w2t, const float* __restrict__ b2,
    const float* __restrict__ lns, const float* __restrict__ lnb,
    float* __restrict__ tok_out) {
    __shared__ unsigned keys[CHUNK];
    __shared__ unsigned hist[256];
    __shared__ int waveTot[4];
    __shared__ unsigned long long cand[2 * KK];
    __shared__ int eqIdx[256];
    __shared__ int selIdx[KK];
    __shared__ float4 localPt[KK];
    __shared__ float w1s[3 * HH];
    __shared__ float b1s[HH];
    __shared__ __align__(16) float hbar[HH];
    __shared__ float partial[256];
    __shared__ float red2[256];
    __shared__ float toks[DD];
    __shared__ unsigned prefS;
    __shared__ int cbS;
    __shared__ int nselS, neqS;
    __shared__ float muS, rstdS;

    const int tid = threadIdx.x;
    // XCD-aware swizzle: each XCD sees only 4 batches' points (768KB -> L2 resident)
    int bid = blockIdx.x;
    int xcd = bid & 7, sub = bid >> 3;
    int b = xcd * 4 + (sub >> 7);
    int g = sub & 127;

    const float* p = pts + (size_t)b * NN * 3;
    float4 c4 = cent_pad[b * GG + g];

    for (int i = tid; i < 3 * HH; i += 256) w1s[i] = w1[i];
    if (tid < HH) b1s[tid] = b1[tid];

    for (int c = 0; c < 2; c++) {
        __syncthreads();  // keys free to overwrite; w1s ready
        // ---- compute dist2 keys for this chunk (matches ref: (c2+p2) - 2*dot, rn ops)
        for (int i = 0; i < 32; i++) {
            int n = i * 256 + tid;
            int gn = c * CHUNK + n;
            float px = p[gn * 3], py = p[gn * 3 + 1], pz = p[gn * 3 + 2];
            float p2 = sq3(px, py, pz);
            float dot = __fadd_rn(__fadd_rn(__fmul_rn(c4.x, px), __fmul_rn(c4.y, py)),
                                  __fmul_rn(c4.z, pz));
            float d = __fsub_rn(__fadd_rn(c4.w, p2), __fmul_rn(2.0f, dot));
            unsigned u = __float_as_uint(d);
            u ^= (u & 0x80000000u) ? 0xFFFFFFFFu : 0x80000000u;  // order-preserving
            keys[n] = u;
        }
        if (tid == 0) { prefS = 0; cbS = 0; }
        __syncthreads();
        // ---- 4-level 8-bit radix select of the 64th smallest key
        for (int lvl = 0; lvl < 4; lvl++) {
            int shift = 24 - 8 * lvl;
            hist[tid] = 0;
            __syncthreads();
            unsigned pref = prefS;
            int cb = cbS;
            for (int i = 0; i < 32; i++) {
                unsigned k = keys[i * 256 + tid];
                bool match = (lvl == 0) || ((k >> (shift + 8)) == pref);
                if (match) atomicAdd(&hist[(k >> shift) & 255u], 1u);
            }
            __syncthreads();
            int cnt = (int)hist[tid];
            int lane = tid & 63, wid = tid >> 6;
            int v = cnt;
#pragma unroll
            for (int off = 1; off < 64; off <<= 1) {
                int o = __shfl_up(v, off);
                if (lane >= off) v += o;
            }
            if (lane == 63) waveTot[wid] = v;
            __syncthreads();
            int basev = 0;
            for (int w = 0; w < wid; w++) basev += waveTot[w];
            int incl = v + basev, excl = incl - cnt;
            if (cb + excl < KK && KK <= cb + incl) {  // exactly one winner
                prefS = (pref << 8) | (unsigned)tid;
                cbS = cb + excl;
            }
            __syncthreads();
        }
        unsigned K64 = prefS;
        int cless = cbS;  // #keys strictly below K64 (<= 63)
        if (tid == 0) { nselS = 0; neqS = 0; }
        __syncthreads();
        // ---- collect: all keys < K64, plus lowest-index ties at K64
        for (int i = 0; i < 32; i++) {
            int n = i * 256 + tid;
            unsigned k = keys[n];
            if (k < K64) {
                int pos = atomicAdd(&nselS, 1);
                cand[c * KK + pos] = ((unsigned long long)k << 32) | (unsigned)(c * CHUNK + n);
            } else if (k == K64) {
                int pos = atomicAdd(&neqS, 1);
                if (pos < 256) eqIdx[pos] = c * CHUNK + n;
            }
        }
        __syncthreads();
        int needE = KK - cless;
        int neq = neqS;
        if (neq <= 256) {
            if (tid < neq) {
                int my = eqIdx[tid];
                int rank = 0;
                for (int j = 0; j < neq; j++) rank += (eqIdx[j] < my);
                if (rank < needE)
                    cand[c * KK + cless + rank] =
                        ((unsigned long long)K64 << 32) | (unsigned)my;
            }
        } else {  // pathological (many bit-identical keys): serial exact fallback
            if (tid == 0) {
                int cnt2 = 0;
                for (int n = 0; n < CHUNK && cnt2 < needE; n++) {
                    if (keys[n] == K64) {
                        cand[c * KK + cless + cnt2] =
                            ((unsigned long long)K64 << 32) | (unsigned)(c * CHUNK + n);
                        cnt2++;
                    }
                }
            }
        }
        __syncthreads();
    }
    // ---- merge: top-64 of 128 candidates by (key, index) rank (all pairs distinct)
    if (tid < 2 * KK) {
        unsigned long long pr = cand[tid];
        int rank = 0;
        for (int j = 0; j < 2 * KK; j++) rank += (cand[j] < pr);
        if (rank < KK) selIdx[rank] = (int)(pr & 0xFFFFFFFFull);
    }
    __syncthreads();
    // ---- gather + local coords
    if (tid < KK) {
        int n = selIdx[tid];
        float px = p[n * 3], py = p[n * 3 + 1], pz = p[n * 3 + 2];
        localPt[tid] = make_float4(px - c4.x, py - c4.y, pz - c4.z, 0.f);
    }
    __syncthreads();
    // ---- layer1 + exact GELU + mean over K (2 threads per feature, 32 pts each)
    {
        int f = tid & 127, half = tid >> 7;
        float wa = w1s[f], wb = w1s[HH + f], wc = w1s[2 * HH + f], bb = b1s[f];
        float s = 0.f;
        for (int k = half * 32; k < half * 32 + 32; k++) {
            float4 lp = localPt[k];
            float a = lp.x * wa + lp.y * wb + lp.z * wc + bb;
            float hh = 0.5f * a * (1.0f + erff(a * 0.70710678118654752440f));
            s += hh;
        }
        partial[tid] = s;
    }
    __syncthreads();
    if (tid < HH) hbar[tid] = (partial[tid] + partial[tid + HH]) * (1.0f / 64.0f);
    __syncthreads();
    // ---- layer2: tokens = hbar @ w2 + b2   (mean commutes with the linear layer)
    for (int f2 = tid; f2 < DD; f2 += 256) {
        const float4* wrow = (const float4*)(w2t + f2 * HH);
        const float4* hb = (const float4*)hbar;
        float acc = b2[f2];
#pragma unroll 8
        for (int q = 0; q < 32; q++) {
            float4 w4 = wrow[q];
            float4 h4 = hb[q];
            acc += h4.x * w4.x + h4.y * w4.y + h4.z * w4.z + h4.w * w4.w;
        }
        toks[f2] = acc;
    }
    __syncthreads();
    // ---- LayerNorm over 384
    {
        float s1 = 0.f, s2 = 0.f;
        for (int f2 = tid; f2 < DD; f2 += 256) {
            float v = toks[f2];
            s1 += v;
            s2 += v * v;
        }
#pragma unroll
        for (int off = 32; off >= 1; off >>= 1) {
            s1 += __shfl_down(s1, off);
            s2 += __shfl_down(s2, off);
        }
        int lane = tid & 63, wid = tid >> 6;
        if (lane == 0) { partial[wid] = s1; red2[wid] = s2; }
        __syncthreads();
        if (tid == 0) {
            float t1 = partial[0] + partial[1] + partial[2] + partial[3];
            float t2 = red2[0] + red2[1] + red2[2] + red2[3];
            float mu = t1 / (float)DD;
            float var = t2 / (float)DD - mu * mu;
            muS = mu;
            rstdS = rsqrtf(var + LN_EPS);
        }
        __syncthreads();
    }
    float mu = muS, rstd = rstdS;
    float* outp = tok_out + ((size_t)b * GG + g) * DD;
    for (int f2 = tid; f2 < DD; f2 += 256) {
        outp[f2] = (toks[f2] - mu) * rstd * lns[f2] + lnb[f2];
    }
}

extern "C" void kernel_launch(void* const* d_in, const int* in_sizes, int n_in,
                              void* d_out, int out_size, void* d_ws, size_t ws_size,
                              hipStream_t stream) {
    const float* pts = (const float*)d_in[0];
    const float* w1 = (const float*)d_in[1];
    const float* b1 = (const float*)d_in[2];
    const float* w2 = (const float*)d_in[3];
    const float* b2 = (const float*)d_in[4];
    const float* lns = (const float*)d_in[5];
    const float* lnb = (const float*)d_in[6];
    float* out = (float*)d_out;

    // ws layout: cent_pad [B*G float4] = 64KB, then w2t [384*128 floats] = 192KB
    float4* cent_pad = (float4*)d_ws;
    float* w2t = (float*)((char*)d_ws + BB * GG * sizeof(float4));

    prep_kernel<<<192, 256, 0, stream>>>(w2, w2t);
    fps_kernel<<<BB, 1024, 0, stream>>>(pts, out, cent_pad);
    group_kernel<<<BB * GG, 256, 0, stream>>>(pts, cent_pad, w1, b1, w2t, b2, lns, lnb,
                                              out + BB * GG * 3);
}

// Round 2
// 629.858 us; speedup vs baseline: 1.5373x; 1.5373x over previous
//
#include <hip/hip_runtime.h>
#include <math.h>

#define BB 32
#define NN 16384
#define GG 128
#define KK 64
#define HH 128
#define DD 384
#define LN_EPS 1e-5f
#define NBUCK 2048
#define CANDCAP 1024

// round-to-nearest sum of 3 squares, matching jnp.sum(x**2, -1) order, no FMA contraction
__device__ __forceinline__ float sq3(float x, float y, float z) {
    return __fadd_rn(__fadd_rn(__fmul_rn(x, x), __fmul_rn(y, y)), __fmul_rn(z, z));
}

// ---------------- prep: transpose w2 [128,384] -> w2t [384,128] ----------------
__global__ void prep_kernel(const float* __restrict__ w2, float* __restrict__ w2t) {
    int i = blockIdx.x * 256 + threadIdx.x;  // over DD*HH = 49152
    if (i < HH * DD) {
        int f = i >> 7;    // 0..383
        int k = i & 127;   // 0..127
        w2t[i] = w2[k * DD + f];
    }
}

// ---------------- FPS: one block per batch, 512 threads, 32 pts/thread ----------------
__global__ __launch_bounds__(512) void fps_kernel(const float* __restrict__ pts,
                                                  float* __restrict__ cent_out,
                                                  float4* __restrict__ cent_pad) {
    const int b = blockIdx.x;
    const int tid = threadIdx.x;
    const float* p = pts + (size_t)b * NN * 3;

    float x[32], y[32], z[32], dist[32];
#pragma unroll
    for (int j = 0; j < 32; j++) {
        int n = j * 512 + tid;
        x[j] = p[n * 3 + 0];
        y[j] = p[n * 3 + 1];
        z[j] = p[n * 3 + 2];
        dist[j] = INFINITY;
    }

    __shared__ float cenx, ceny, cenz;
    __shared__ float wv[8];
    __shared__ int wi[8];

    if (tid == 0) { cenx = p[0]; ceny = p[1]; cenz = p[2]; }
    __syncthreads();

    for (int it = 0; it < GG; it++) {
        float cx = cenx, cy = ceny, cz = cenz;
        if (tid == 0) {
            float* co = cent_out + ((size_t)b * GG + it) * 3;
            co[0] = cx; co[1] = cy; co[2] = cz;
            cent_pad[b * GG + it] = make_float4(cx, cy, cz, sq3(cx, cy, cz));
        }
        // distance update + 4-chain local argmax (strict > keeps lowest index per chain)
        float bv0 = -INFINITY, bv1 = -INFINITY, bv2 = -INFINITY, bv3 = -INFINITY;
        int bi0 = 0, bi1 = 0, bi2 = 0, bi3 = 0;
#pragma unroll
        for (int j = 0; j < 32; j++) {
            float dx = __fsub_rn(x[j], cx);
            float dy = __fsub_rn(y[j], cy);
            float dz = __fsub_rn(z[j], cz);
            float d = sq3(dx, dy, dz);
            float dj = fminf(dist[j], d);
            dist[j] = dj;
            int n = j * 512 + tid;
            switch (j & 3) {
                case 0: if (dj > bv0) { bv0 = dj; bi0 = n; } break;
                case 1: if (dj > bv1) { bv1 = dj; bi1 = n; } break;
                case 2: if (dj > bv2) { bv2 = dj; bi2 = n; } break;
                case 3: if (dj > bv3) { bv3 = dj; bi3 = n; } break;
            }
        }
        float fv = bv0; int fi = bi0;
        if (bv1 > fv || (bv1 == fv && bi1 < fi)) { fv = bv1; fi = bi1; }
        if (bv2 > fv || (bv2 == fv && bi2 < fi)) { fv = bv2; fi = bi2; }
        if (bv3 > fv || (bv3 == fv && bi3 < fi)) { fv = bv3; fi = bi3; }
        // wave (64-lane) argmax reduce, lower index wins ties
#pragma unroll
        for (int off = 32; off >= 1; off >>= 1) {
            float ov = __shfl_down(fv, off);
            int oi = __shfl_down(fi, off);
            if (ov > fv || (ov == fv && oi < fi)) { fv = ov; fi = oi; }
        }
        int lane = tid & 63, wid = tid >> 6;
        if (lane == 0) { wv[wid] = fv; wi[wid] = fi; }
        __syncthreads();
        if (tid == 0) {
            float gv = wv[0]; int gi = wi[0];
            for (int w = 1; w < 8; w++) {
                if (wv[w] > gv || (wv[w] == gv && wi[w] < gi)) { gv = wv[w]; gi = wi[w]; }
            }
            // winner's coords: single L2-hit read (batch points are L2-resident)
            const float* wp = p + (size_t)gi * 3;
            cenx = wp[0]; ceny = wp[1]; cenz = wp[2];
        }
        __syncthreads();
    }
}

// ---------------- group kernel: dist2 + exact top-64 + MLP + mean + LN ----------------
__global__ __launch_bounds__(256) void group_kernel(
    const float* __restrict__ pts, const float4* __restrict__ cent_pad,
    const float* __restrict__ w1, const float* __restrict__ b1,
    const float* __restrict__ w2t, const float* __restrict__ b2,
    const float* __restrict__ lns, const float* __restrict__ lnb,
    float* __restrict__ tok_out) {
    __shared__ __align__(16) unsigned hist[NBUCK];
    __shared__ unsigned long long cand[CANDCAP];
    __shared__ int selIdx[KK];
    __shared__ float4 localPt[KK];
    __shared__ float w1s[3 * HH];
    __shared__ float b1s[HH];
    __shared__ __align__(16) float hbar[HH];
    __shared__ float partial[256];
    __shared__ float red2[8];
    __shared__ float toks[DD];
    __shared__ int waveSum[4];
    __shared__ unsigned long long wmin[4];
    __shared__ unsigned TA_S;
    __shared__ int cntS;
    __shared__ unsigned long long lastS;
    __shared__ float muS, rstdS;

    const int tid = threadIdx.x;
    // XCD-aware swizzle: each XCD sees only 4 batches' points (768KB -> L2 resident)
    int bid = blockIdx.x;
    int xcd = bid & 7, sub = bid >> 3;
    int b = xcd * 4 + (sub >> 7);
    int g = sub & 127;

    const float* p = pts + (size_t)b * NN * 3;
    float4 c4 = cent_pad[b * GG + g];

    for (int i = tid; i < 3 * HH; i += 256) w1s[i] = w1[i];
    if (tid < HH) b1s[tid] = b1[tid];
    for (int i = tid; i < NBUCK; i += 256) hist[i] = 0;
    if (tid == 0) cntS = 0;
    __syncthreads();

    // ---- one pass: compute all 64 keys into registers + 2048-bucket histogram
    unsigned key[64];
#pragma unroll
    for (int i = 0; i < 64; i++) {
        int n = i * 256 + tid;
        float px = p[n * 3], py = p[n * 3 + 1], pz = p[n * 3 + 2];
        float p2 = sq3(px, py, pz);
        float dot = __fadd_rn(__fadd_rn(__fmul_rn(c4.x, px), __fmul_rn(c4.y, py)),
                              __fmul_rn(c4.z, pz));
        float d = __fsub_rn(__fadd_rn(c4.w, p2), __fmul_rn(2.0f, dot));
        unsigned u = __float_as_uint(d);
        u ^= (u & 0x80000000u) ? 0xFFFFFFFFu : 0x80000000u;  // order-preserving
        key[i] = u;
        atomicAdd(&hist[u >> 21], 1u);
    }
    __syncthreads();

    // ---- find boundary bucket: smallest T with cumcount(<=T) >= 64
    {
        uint4 h0 = ((const uint4*)hist)[tid * 2];
        uint4 h1 = ((const uint4*)hist)[tid * 2 + 1];
        int loc[8] = {(int)h0.x, (int)h0.y, (int)h0.z, (int)h0.w,
                      (int)h1.x, (int)h1.y, (int)h1.z, (int)h1.w};
        int s = 0;
#pragma unroll
        for (int j = 0; j < 8; j++) s += loc[j];
        int lane = tid & 63, wid = tid >> 6;
        int v = s;
#pragma unroll
        for (int off = 1; off < 64; off <<= 1) {
            int o = __shfl_up(v, off);
            if (lane >= off) v += o;
        }
        if (lane == 63) waveSum[wid] = v;
        __syncthreads();
        int base = 0;
        for (int w = 0; w < wid; w++) base += waveSum[w];
        int c = base + v - s;  // exclusive prefix at this thread's first bucket
#pragma unroll
        for (int j = 0; j < 8; j++) {
            if (c < KK && c + loc[j] >= KK) TA_S = (unsigned)(tid * 8 + j);
            c += loc[j];
        }
        __syncthreads();
    }
    unsigned TA = TA_S;

    // ---- collect candidates: all keys in buckets <= TA (expected ~100)
#pragma unroll
    for (int i = 0; i < 64; i++) {
        unsigned u = key[i];
        if ((u >> 21) <= TA) {
            int pos = atomicAdd(&cntS, 1);
            if (pos < CANDCAP)
                cand[pos] = ((unsigned long long)u << 32) | (unsigned)(i * 256 + tid);
        }
    }
    __syncthreads();
    int cnt = cntS;  // >= 64 by construction

    if (cnt <= CANDCAP) {
        // ---- exact rank-select of the 64 lexicographically smallest (key,idx)
        for (int c0 = tid; c0 < cnt; c0 += 256) {
            unsigned long long pr = cand[c0];
            int rank = 0;
            for (int j = 0; j < cnt; j++) rank += (cand[j] < pr);
            if (rank < KK) selIdx[rank] = (int)(unsigned)pr;
        }
        __syncthreads();
    } else {
        // ---- pathological fallback: exact 64-round min-extraction from registers
        if (tid == 0) lastS = 0ull;
        __syncthreads();
        for (int r = 0; r < KK; r++) {
            unsigned long long last = lastS;
            unsigned long long best = 0xFFFFFFFFFFFFFFFFull;
#pragma unroll
            for (int i = 0; i < 64; i++) {
                unsigned long long pr =
                    ((unsigned long long)key[i] << 32) | (unsigned)(i * 256 + tid);
                if ((r == 0 || pr > last) && pr < best) best = pr;
            }
            unsigned blo = (unsigned)best, bhi = (unsigned)(best >> 32);
#pragma unroll
            for (int off = 32; off >= 1; off >>= 1) {
                unsigned olo = __shfl_down(blo, off);
                unsigned ohi = __shfl_down(bhi, off);
                unsigned long long ob = ((unsigned long long)ohi << 32) | olo;
                unsigned long long cur = ((unsigned long long)bhi << 32) | blo;
                if (ob < cur) { blo = olo; bhi = ohi; }
            }
            int lane = tid & 63, wid = tid >> 6;
            if (lane == 0) wmin[wid] = ((unsigned long long)bhi << 32) | blo;
            __syncthreads();
            if (tid == 0) {
                unsigned long long m = wmin[0];
                for (int w = 1; w < 4; w++) if (wmin[w] < m) m = wmin[w];
                selIdx[r] = (int)(unsigned)m;
                lastS = m;
            }
            __syncthreads();
        }
    }

    // ---- gather + local coords
    if (tid < KK) {
        int n = selIdx[tid];
        float px = p[n * 3], py = p[n * 3 + 1], pz = p[n * 3 + 2];
        localPt[tid] = make_float4(px - c4.x, py - c4.y, pz - c4.z, 0.f);
    }
    __syncthreads();
    // ---- layer1 + exact GELU + mean over K (2 threads per feature, 32 pts each)
    {
        int f = tid & 127, half = tid >> 7;
        float wa = w1s[f], wb = w1s[HH + f], wc = w1s[2 * HH + f], bb = b1s[f];
        float s = 0.f;
        for (int k = half * 32; k < half * 32 + 32; k++) {
            float4 lp = localPt[k];
            float a = lp.x * wa + lp.y * wb + lp.z * wc + bb;
            float hh = 0.5f * a * (1.0f + erff(a * 0.70710678118654752440f));
            s += hh;
        }
        partial[tid] = s;
    }
    __syncthreads();
    if (tid < HH) hbar[tid] = (partial[tid] + partial[tid + HH]) * (1.0f / 64.0f);
    __syncthreads();
    // ---- layer2: tokens = hbar @ w2 + b2   (mean commutes with the linear layer)
    for (int f2 = tid; f2 < DD; f2 += 256) {
        const float4* wrow = (const float4*)(w2t + f2 * HH);
        const float4* hb = (const float4*)hbar;
        float acc = b2[f2];
#pragma unroll 8
        for (int q = 0; q < 32; q++) {
            float4 w4 = wrow[q];
            float4 h4 = hb[q];
            acc += h4.x * w4.x + h4.y * w4.y + h4.z * w4.z + h4.w * w4.w;
        }
        toks[f2] = acc;
    }
    __syncthreads();
    // ---- LayerNorm over 384
    {
        float s1 = 0.f, s2 = 0.f;
        for (int f2 = tid; f2 < DD; f2 += 256) {
            float v = toks[f2];
            s1 += v;
            s2 += v * v;
        }
#pragma unroll
        for (int off = 32; off >= 1; off >>= 1) {
            s1 += __shfl_down(s1, off);
            s2 += __shfl_down(s2, off);
        }
        int lane = tid & 63, wid = tid >> 6;
        if (lane == 0) { partial[wid] = s1; red2[wid] = s2; }
        __syncthreads();
        if (tid == 0) {
            float t1 = partial[0] + partial[1] + partial[2] + partial[3];
            float t2 = red2[0] + red2[1] + red2[2] + red2[3];
            float mu = t1 / (float)DD;
            float var = t2 / (float)DD - mu * mu;
            muS = mu;
            rstdS = rsqrtf(var + LN_EPS);
        }
        __syncthreads();
    }
    float mu = muS, rstd = rstdS;
    float* outp = tok_out + ((size_t)b * GG + g) * DD;
    for (int f2 = tid; f2 < DD; f2 += 256) {
        outp[f2] = (toks[f2] - mu) * rstd * lns[f2] + lnb[f2];
    }
}

extern "C" void kernel_launch(void* const* d_in, const int* in_sizes, int n_in,
                              void* d_out, int out_size, void* d_ws, size_t ws_size,
                              hipStream_t stream) {
    const float* pts = (const float*)d_in[0];
    const float* w1 = (const float*)d_in[1];
    const float* b1 = (const float*)d_in[2];
    const float* w2 = (const float*)d_in[3];
    const float* b2 = (const float*)d_in[4];
    const float* lns = (const float*)d_in[5];
    const float* lnb = (const float*)d_in[6];
    float* out = (float*)d_out;

    // ws layout: cent_pad [B*G float4] = 64KB, then w2t [384*128 floats] = 192KB
    float4* cent_pad = (float4*)d_ws;
    float* w2t = (float*)((char*)d_ws + BB * GG * sizeof(float4));

    prep_kernel<<<192, 256, 0, stream>>>(w2, w2t);
    fps_kernel<<<BB, 512, 0, stream>>>(pts, out, cent_pad);
    group_kernel<<<BB * GG, 256, 0, stream>>>(pts, cent_pad, w1, b1, w2t, b2, lns, lnb,
                                              out + BB * GG * 3);
}

// Round 3
// 533.615 us; speedup vs baseline: 1.8145x; 1.1804x over previous
//
#include <hip/hip_runtime.h>
#include <math.h>

#define BB 32
#define NN 16384
#define GG 128
#define KK 64
#define HH 128
#define DD 384
#define LN_EPS 1e-5f
#define NBUCK 2048
#define CANDCAP 1024

// round-to-nearest sum of 3 squares, matching jnp.sum(x**2, -1) order, no FMA contraction
__device__ __forceinline__ float sq3(float x, float y, float z) {
    return __fadd_rn(__fadd_rn(__fmul_rn(x, x), __fmul_rn(y, y)), __fmul_rn(z, z));
}

// order-preserving uint key of dist2, same formula/rounding as reference
__device__ __forceinline__ unsigned distkey(float px, float py, float pz, float4 c4) {
    float p2 = sq3(px, py, pz);
    float dot = __fadd_rn(__fadd_rn(__fmul_rn(c4.x, px), __fmul_rn(c4.y, py)),
                          __fmul_rn(c4.z, pz));
    float d = __fsub_rn(__fadd_rn(c4.w, p2), __fmul_rn(2.0f, dot));
    unsigned u = __float_as_uint(d);
    return u ^ ((u & 0x80000000u) ? 0xFFFFFFFFu : 0x80000000u);
}

// ---------------- prep: transpose w2 [128,384] -> w2t [384,128] ----------------
__global__ void prep_kernel(const float* __restrict__ w2, float* __restrict__ w2t) {
    int i = blockIdx.x * 256 + threadIdx.x;  // over DD*HH = 49152
    if (i < HH * DD) {
        int f = i >> 7;    // 0..383
        int k = i & 127;   // 0..127
        w2t[i] = w2[k * DD + f];
    }
}

// ---------------- FPS: one block per batch, 512 threads, 32 pts/thread ----------------
// __launch_bounds__(512,2): 2 waves/SIMD -> 256-VGPR budget so x/y/z/dist stay in
// registers (round-2 showed VGPR=84 => the 128-float point cache was spilled).
__global__ __launch_bounds__(512, 2) void fps_kernel(const float* __restrict__ pts,
                                                     float* __restrict__ cent_out,
                                                     float4* __restrict__ cent_pad) {
    const int b = blockIdx.x;
    const int tid = threadIdx.x;
    const float* p = pts + (size_t)b * NN * 3;
    const float4* p4 = (const float4*)p;

    // thread owns quads q = j*512+tid (j=0..7): points 4q..4q+3, loaded as 3 float4
    float x[32], y[32], z[32], dist[32];
#pragma unroll
    for (int j = 0; j < 8; j++) {
        int q = j * 512 + tid;
        float4 A = p4[3 * q], B = p4[3 * q + 1], C = p4[3 * q + 2];
        x[j * 4 + 0] = A.x; y[j * 4 + 0] = A.y; z[j * 4 + 0] = A.z;
        x[j * 4 + 1] = A.w; y[j * 4 + 1] = B.x; z[j * 4 + 1] = B.y;
        x[j * 4 + 2] = B.z; y[j * 4 + 2] = B.w; z[j * 4 + 2] = C.x;
        x[j * 4 + 3] = C.y; y[j * 4 + 3] = C.z; z[j * 4 + 3] = C.w;
#pragma unroll
        for (int t = 0; t < 4; t++) dist[j * 4 + t] = INFINITY;
    }

    __shared__ unsigned long long slot[GG];  // one pre-zeroed slot per iteration
    for (int i = tid; i < GG; i += 512) slot[i] = 0ull;
    __syncthreads();

    float cx = p[0], cy = p[1], cz = p[2];  // deterministic start at index 0

    for (int it = 0; it < GG; it++) {
        if (tid == 0) {
            float* co = cent_out + ((size_t)b * GG + it) * 3;
            co[0] = cx; co[1] = cy; co[2] = cz;
            cent_pad[b * GG + it] = make_float4(cx, cy, cz, sq3(cx, cy, cz));
        }
        if (it == GG - 1) break;  // last argmax unused

        // distance update + 4-chain local argmax (strict > keeps lowest index per chain)
        float bv0 = -INFINITY, bv1 = -INFINITY, bv2 = -INFINITY, bv3 = -INFINITY;
        int bi0 = 0, bi1 = 0, bi2 = 0, bi3 = 0;
#pragma unroll
        for (int j = 0; j < 8; j++) {
            int nb = 4 * (j * 512 + tid);
#pragma unroll
            for (int t = 0; t < 4; t++) {
                int r = j * 4 + t;
                float dx = __fsub_rn(x[r], cx);
                float dy = __fsub_rn(y[r], cy);
                float dz = __fsub_rn(z[r], cz);
                float d = sq3(dx, dy, dz);
                float dj = fminf(dist[r], d);
                dist[r] = dj;
                int n = nb + t;
                switch (t) {
                    case 0: if (dj > bv0) { bv0 = dj; bi0 = n; } break;
                    case 1: if (dj > bv1) { bv1 = dj; bi1 = n; } break;
                    case 2: if (dj > bv2) { bv2 = dj; bi2 = n; } break;
                    case 3: if (dj > bv3) { bv3 = dj; bi3 = n; } break;
                }
            }
        }
        float fv = bv0; int fi = bi0;
        if (bv1 > fv || (bv1 == fv && bi1 < fi)) { fv = bv1; fi = bi1; }
        if (bv2 > fv || (bv2 == fv && bi2 < fi)) { fv = bv2; fi = bi2; }
        if (bv3 > fv || (bv3 == fv && bi3 < fi)) { fv = bv3; fi = bi3; }
        // wave (64-lane) argmax reduce, lower index wins ties
#pragma unroll
        for (int off = 32; off >= 1; off >>= 1) {
            float ov = __shfl_down(fv, off);
            int oi = __shfl_down(fi, off);
            if (ov > fv || (ov == fv && oi < fi)) { fv = ov; fi = oi; }
        }
        // dist >= 0 so float bits are order-monotone; ~idx -> lowest index wins max
        if ((tid & 63) == 0) {
            unsigned long long packed =
                ((unsigned long long)__float_as_uint(fv) << 32) |
                (unsigned)(0xFFFFFFFFu - (unsigned)fi);
            atomicMax(&slot[it], packed);
        }
        __syncthreads();  // the only barrier per iteration
        unsigned long long w = slot[it];
        int idx = (int)(0xFFFFFFFFu - (unsigned)w);
        const float* wp = p + (size_t)idx * 3;  // broadcast same-address load, L2-hit
        cx = wp[0]; cy = wp[1]; cz = wp[2];
    }
}

// ---------------- group kernel: dist2 + exact top-64 + MLP + mean + LN ----------------
// Keys are recomputed instead of cached (round-2: key[64] live across barriers
// spilled to scratch at VGPR=76). hist/cand overlay saves 8KB LDS.
__global__ __launch_bounds__(256, 6) void group_kernel(
    const float* __restrict__ pts, const float4* __restrict__ cent_pad,
    const float* __restrict__ w1, const float* __restrict__ b1,
    const float* __restrict__ w2t, const float* __restrict__ b2,
    const float* __restrict__ lns, const float* __restrict__ lnb,
    float* __restrict__ tok_out) {
    __shared__ __align__(16) union {
        unsigned hist[NBUCK];              // phase 1-2
        unsigned long long cand[CANDCAP];  // phase 3+ (hist dead after scan)
    } sh;
    __shared__ int selIdx[KK];
    __shared__ float4 localPt[KK];
    __shared__ float w1s[3 * HH];
    __shared__ float b1s[HH];
    __shared__ __align__(16) float hbar[HH];
    __shared__ float partial[256];
    __shared__ float red2[8];
    __shared__ float toks[DD];
    __shared__ int waveSum[4];
    __shared__ unsigned long long wmin[4];
    __shared__ unsigned TA_S;
    __shared__ int cntS;
    __shared__ unsigned long long lastS;
    __shared__ float muS, rstdS;

    const int tid = threadIdx.x;
    // XCD-aware swizzle: each XCD sees only 4 batches' points (768KB -> L2 resident)
    int bid = blockIdx.x;
    int xcd = bid & 7, sub = bid >> 3;
    int b = xcd * 4 + (sub >> 7);
    int g = sub & 127;

    const float* p = pts + (size_t)b * NN * 3;
    const float4* p4 = (const float4*)p;
    float4 c4 = cent_pad[b * GG + g];

    for (int i = tid; i < 3 * HH; i += 256) w1s[i] = w1[i];
    if (tid < HH) b1s[tid] = b1[tid];
    for (int i = tid; i < NBUCK; i += 256) sh.hist[i] = 0;
    if (tid == 0) cntS = 0;
    __syncthreads();

    // ---- pass 1: histogram of 11-bit key prefixes (keys recomputed later, not stored)
    for (int i = 0; i < 16; i++) {
        int t4 = i * 256 + tid;  // quad id; points 4*t4 .. 4*t4+3
        float4 A = p4[3 * t4], B = p4[3 * t4 + 1], C = p4[3 * t4 + 2];
        unsigned k0 = distkey(A.x, A.y, A.z, c4);
        unsigned k1 = distkey(A.w, B.x, B.y, c4);
        unsigned k2 = distkey(B.z, B.w, C.x, c4);
        unsigned k3 = distkey(C.y, C.z, C.w, c4);
        atomicAdd(&sh.hist[k0 >> 21], 1u);
        atomicAdd(&sh.hist[k1 >> 21], 1u);
        atomicAdd(&sh.hist[k2 >> 21], 1u);
        atomicAdd(&sh.hist[k3 >> 21], 1u);
    }
    __syncthreads();

    // ---- find boundary bucket: smallest T with cumcount(<=T) >= 64
    {
        uint4 h0 = ((const uint4*)sh.hist)[tid * 2];
        uint4 h1 = ((const uint4*)sh.hist)[tid * 2 + 1];
        int loc[8] = {(int)h0.x, (int)h0.y, (int)h0.z, (int)h0.w,
                      (int)h1.x, (int)h1.y, (int)h1.z, (int)h1.w};
        int s = 0;
#pragma unroll
        for (int j = 0; j < 8; j++) s += loc[j];
        int lane = tid & 63, wid = tid >> 6;
        int v = s;
#pragma unroll
        for (int off = 1; off < 64; off <<= 1) {
            int o = __shfl_up(v, off);
            if (lane >= off) v += o;
        }
        if (lane == 63) waveSum[wid] = v;
        __syncthreads();
        int base = 0;
        for (int w = 0; w < wid; w++) base += waveSum[w];
        int c = base + v - s;  // exclusive prefix at this thread's first bucket
#pragma unroll
        for (int j = 0; j < 8; j++) {
            if (c < KK && c + loc[j] >= KK) TA_S = (unsigned)(tid * 8 + j);
            c += loc[j];
        }
        __syncthreads();
    }
    unsigned TA = TA_S;

    // ---- pass 2: recompute keys, collect candidates in buckets <= TA (~330 expected)
    for (int i = 0; i < 16; i++) {
        int t4 = i * 256 + tid;
        float4 A = p4[3 * t4], B = p4[3 * t4 + 1], C = p4[3 * t4 + 2];
        unsigned k[4];
        k[0] = distkey(A.x, A.y, A.z, c4);
        k[1] = distkey(A.w, B.x, B.y, c4);
        k[2] = distkey(B.z, B.w, C.x, c4);
        k[3] = distkey(C.y, C.z, C.w, c4);
#pragma unroll
        for (int q = 0; q < 4; q++) {
            if ((k[q] >> 21) <= TA) {
                int pos = atomicAdd(&cntS, 1);
                if (pos < CANDCAP)
                    sh.cand[pos] =
                        ((unsigned long long)k[q] << 32) | (unsigned)(4 * t4 + q);
            }
        }
    }
    __syncthreads();
    int cnt = cntS;  // >= 64 by construction

    if (cnt <= CANDCAP) {
        // ---- exact rank-select of the 64 lexicographically smallest (key,idx)
        for (int c0 = tid; c0 < cnt; c0 += 256) {
            unsigned long long pr = sh.cand[c0];
            int rank = 0;
            for (int j = 0; j < cnt; j++) rank += (sh.cand[j] < pr);
            if (rank < KK) selIdx[rank] = (int)(unsigned)pr;
        }
        __syncthreads();
    } else {
        // ---- pathological fallback (never triggers on real data): exact 64-round
        // min-extraction, keys recomputed each round
        if (tid == 0) lastS = 0ull;
        __syncthreads();
        for (int r = 0; r < KK; r++) {
            unsigned long long last = lastS;
            unsigned long long best = 0xFFFFFFFFFFFFFFFFull;
            for (int i = 0; i < 16; i++) {
                int t4 = i * 256 + tid;
                float4 A = p4[3 * t4], B = p4[3 * t4 + 1], C = p4[3 * t4 + 2];
                unsigned k[4];
                k[0] = distkey(A.x, A.y, A.z, c4);
                k[1] = distkey(A.w, B.x, B.y, c4);
                k[2] = distkey(B.z, B.w, C.x, c4);
                k[3] = distkey(C.y, C.z, C.w, c4);
#pragma unroll
                for (int q = 0; q < 4; q++) {
                    unsigned long long pr =
                        ((unsigned long long)k[q] << 32) | (unsigned)(4 * t4 + q);
                    if ((r == 0 || pr > last) && pr < best) best = pr;
                }
            }
            unsigned blo = (unsigned)best, bhi = (unsigned)(best >> 32);
#pragma unroll
            for (int off = 32; off >= 1; off >>= 1) {
                unsigned olo = __shfl_down(blo, off);
                unsigned ohi = __shfl_down(bhi, off);
                unsigned long long ob = ((unsigned long long)ohi << 32) | olo;
                unsigned long long cur = ((unsigned long long)bhi << 32) | blo;
                if (ob < cur) { blo = olo; bhi = ohi; }
            }
            int lane = tid & 63, wid = tid >> 6;
            if (lane == 0) wmin[wid] = ((unsigned long long)bhi << 32) | blo;
            __syncthreads();
            if (tid == 0) {
                unsigned long long m = wmin[0];
                for (int w = 1; w < 4; w++) if (wmin[w] < m) m = wmin[w];
                selIdx[r] = (int)(unsigned)m;
                lastS = m;
            }
            __syncthreads();
        }
    }

    // ---- gather + local coords
    if (tid < KK) {
        int n = selIdx[tid];
        float px = p[n * 3], py = p[n * 3 + 1], pz = p[n * 3 + 2];
        localPt[tid] = make_float4(px - c4.x, py - c4.y, pz - c4.z, 0.f);
    }
    __syncthreads();
    // ---- layer1 + exact GELU + mean over K (2 threads per feature, 32 pts each)
    {
        int f = tid & 127, half = tid >> 7;
        float wa = w1s[f], wb = w1s[HH + f], wc = w1s[2 * HH + f], bb = b1s[f];
        float s = 0.f;
        for (int k = half * 32; k < half * 32 + 32; k++) {
            float4 lp = localPt[k];
            float a = lp.x * wa + lp.y * wb + lp.z * wc + bb;
            float hh = 0.5f * a * (1.0f + erff(a * 0.70710678118654752440f));
            s += hh;
        }
        partial[tid] = s;
    }
    __syncthreads();
    if (tid < HH) hbar[tid] = (partial[tid] + partial[tid + HH]) * (1.0f / 64.0f);
    __syncthreads();
    // ---- layer2: tokens = hbar @ w2 + b2   (mean commutes with the linear layer)
    for (int f2 = tid; f2 < DD; f2 += 256) {
        const float4* wrow = (const float4*)(w2t + f2 * HH);
        const float4* hb = (const float4*)hbar;
        float acc = b2[f2];
#pragma unroll 8
        for (int q = 0; q < 32; q++) {
            float4 w4 = wrow[q];
            float4 h4 = hb[q];
            acc += h4.x * w4.x + h4.y * w4.y + h4.z * w4.z + h4.w * w4.w;
        }
        toks[f2] = acc;
    }
    __syncthreads();
    // ---- LayerNorm over 384
    {
        float s1 = 0.f, s2 = 0.f;
        for (int f2 = tid; f2 < DD; f2 += 256) {
            float v = toks[f2];
            s1 += v;
            s2 += v * v;
        }
#pragma unroll
        for (int off = 32; off >= 1; off >>= 1) {
            s1 += __shfl_down(s1, off);
            s2 += __shfl_down(s2, off);
        }
        int lane = tid & 63, wid = tid >> 6;
        if (lane == 0) { partial[wid] = s1; red2[wid] = s2; }
        __syncthreads();
        if (tid == 0) {
            float t1 = partial[0] + partial[1] + partial[2] + partial[3];
            float t2 = red2[0] + red2[1] + red2[2] + red2[3];
            float mu = t1 / (float)DD;
            float var = t2 / (float)DD - mu * mu;
            muS = mu;
            rstdS = rsqrtf(var + LN_EPS);
        }
        __syncthreads();
    }
    float mu = muS, rstd = rstdS;
    float* outp = tok_out + ((size_t)b * GG + g) * DD;
    for (int f2 = tid; f2 < DD; f2 += 256) {
        outp[f2] = (toks[f2] - mu) * rstd * lns[f2] + lnb[f2];
    }
}

extern "C" void kernel_launch(void* const* d_in, const int* in_sizes, int n_in,
                              void* d_out, int out_size, void* d_ws, size_t ws_size,
                              hipStream_t stream) {
    const float* pts = (const float*)d_in[0];
    const float* w1 = (const float*)d_in[1];
    const float* b1 = (const float*)d_in[2];
    const float* w2 = (const float*)d_in[3];
    const float* b2 = (const float*)d_in[4];
    const float* lns = (const float*)d_in[5];
    const float* lnb = (const float*)d_in[6];
    float* out = (float*)d_out;

    // ws layout: cent_pad [B*G float4] = 64KB, then w2t [384*128 floats] = 192KB
    float4* cent_pad = (float4*)d_ws;
    float* w2t = (float*)((char*)d_ws + BB * GG * sizeof(float4));

    prep_kernel<<<192, 256, 0, stream>>>(w2, w2t);
    fps_kernel<<<BB, 512, 0, stream>>>(pts, out, cent_pad);
    group_kernel<<<BB * GG, 256, 0, stream>>>(pts, cent_pad, w1, b1, w2t, b2, lns, lnb,
                                              out + BB * GG * 3);
}